// Round 7
// baseline (141.896 us; speedup 1.0000x reference)
//
#include <hip/hip_runtime.h>

#define B_ 8
#define D_ 256
#define N_ 32768
#define F_ 256
#define K_ 16
#define NCH 64        // K1 chunks per batch
#define CHN 512       // K1 n per chunk
#define NR 4          // agg n-ranges
#define NRN 8192      // n per range

__device__ __forceinline__ float sum4(float4 v) { return v.x + v.y + v.z + v.w; }
__device__ __forceinline__ float dot4(float4 a, float4 b) {
  return a.x * b.x + a.y * b.y + a.z * b.z + a.w * b.w;
}

// ---------------------------------------------------------------------------
// K1 (R2-verbatim): e[b][n] = exp(-(q . k_n)/16) + per-chunk scalars
// (Se, Se2, Se3). 512 blocks (8 b x 64 chunks of 512 n) x 512 threads.
// ---------------------------------------------------------------------------
__global__ __launch_bounds__(512) void expsim_kernel(
    const float* __restrict__ q, const float* __restrict__ keys,
    float* __restrict__ e, float* __restrict__ pp) {
  const int b = blockIdx.x >> 6;
  const int chunk = blockIdx.x & 63;
  const int t = threadIdx.x;
  const int c = t & 127;
  const int g = t >> 7;
  __shared__ float qs[D_];
  __shared__ float4 part[3][128];
  __shared__ float pr[8][3];
  if (t < D_) qs[t] = q[b * D_ + t];
  __syncthreads();
  const int n0 = chunk * CHN + c * 4;
  const float* kp = keys + (size_t)b * D_ * N_ + (size_t)(g * 64) * N_ + n0;
  const float* qg = qs + g * 64;
  float ax = 0.f, ay = 0.f, az = 0.f, aw = 0.f;
#pragma unroll 8
  for (int d = 0; d < 64; ++d) {
    float4 kv = *reinterpret_cast<const float4*>(kp + (size_t)d * N_);
    float qd = qg[d];
    ax += qd * kv.x; ay += qd * kv.y; az += qd * kv.z; aw += qd * kv.w;
  }
  if (g > 0) part[g - 1][c] = make_float4(ax, ay, az, aw);
  __syncthreads();
  float s1 = 0.f, s2 = 0.f, s3 = 0.f;
  if (g == 0) {
    float4 p1 = part[0][c], p2 = part[1][c], p3 = part[2][c];
    float4 ev;
    ev.x = __expf(-0.0625f * (ax + p1.x + p2.x + p3.x));
    ev.y = __expf(-0.0625f * (ay + p1.y + p2.y + p3.y));
    ev.z = __expf(-0.0625f * (az + p1.z + p2.z + p3.z));
    ev.w = __expf(-0.0625f * (aw + p1.w + p2.w + p3.w));
    *reinterpret_cast<float4*>(e + (size_t)b * N_ + n0) = ev;
    float4 e2 = make_float4(ev.x * ev.x, ev.y * ev.y, ev.z * ev.z, ev.w * ev.w);
    s1 = sum4(ev);
    s2 = sum4(e2);
    s3 = e2.x * ev.x + e2.y * ev.y + e2.z * ev.z + e2.w * ev.w;
  }
#pragma unroll
  for (int off = 32; off > 0; off >>= 1) {
    s1 += __shfl_xor(s1, off, 64);
    s2 += __shfl_xor(s2, off, 64);
    s3 += __shfl_xor(s3, off, 64);
  }
  if ((t & 63) == 0) { pr[t >> 6][0] = s1; pr[t >> 6][1] = s2; pr[t >> 6][2] = s3; }
  __syncthreads();
  if (t == 0) {
    float r1 = 0.f, r2 = 0.f, r3 = 0.f;
#pragma unroll
    for (int w = 0; w < 8; ++w) { r1 += pr[w][0]; r2 += pr[w][1]; r3 += pr[w][2]; }
    pp[0 * B_ * NCH + b * NCH + chunk] = r1;
    pp[1 * B_ * NCH + b * NCH + chunk] = r2;
    pp[2 * B_ * NCH + b * NCH + chunk] = r3;
  }
}

// ---------------------------------------------------------------------------
// K2: n-split moment aggregation. Block = (b, f-group of 8, n-range of 8192).
// 1024 blocks x 256 threads (4 blocks/CU). Per n-step: 1 e-load (reused in
// registers for all rows) + 8 value-row loads; vals[16] register accumulators;
// per-row n-step rotation decorrelates the 128KB-strided streams.
// e traffic: 32KB/block = 32 MB total (vs 1 GB L2 re-read in R2).
// ---------------------------------------------------------------------------
__global__ __launch_bounds__(256, 4) void agg_kernel(
    const float* __restrict__ e, const float* __restrict__ values,
    float* __restrict__ p0, float* __restrict__ p1) {
  const int bid = blockIdx.x;
  const int b = bid & 7;
  const int fg = (bid >> 3) & 31;
  const int nr = bid >> 8;           // 0..3
  const int t = threadIdx.x;
  const int f0 = fg * 8;
  const size_t nbase = (size_t)nr * NRN + t * 4;
  const float* eb = e + (size_t)b * N_ + nbase;
  const float* vb = values + ((size_t)b * F_ + f0) * N_ + nbase;

  float vals[16];
#pragma unroll
  for (int i = 0; i < 16; ++i) vals[i] = 0.f;

  // 8 n-steps of 1024 floats each; row j visits steps in rotated order
#pragma unroll
  for (int s = 0; s < 8; ++s) {
    float4 ev[8];   // e for the step each row uses this iteration
    // row j uses step (s + j) & 7; e for that step:
#pragma unroll
    for (int j = 0; j < 8; ++j) {
      const int sj = (s + j) & 7;
      float4 v4 = *reinterpret_cast<const float4*>(vb + (size_t)j * N_ + sj * 1024);
      float4 e4 = *reinterpret_cast<const float4*>(eb + sj * 1024);
      vals[j]     += sum4(v4);
      vals[8 + j] += dot4(v4, e4);
    }
    (void)ev;
  }

  // verified merge-butterfly (R5): after 4 levels + shfl16/32,
  // lanes 0-7 hold m0[f=lane], lanes 8-15 hold m1[f=lane-8]
#pragma unroll
  for (int lev = 0; lev < 4; ++lev) {
    const int sft = 8 >> lev;
    const int nv = 8 >> lev;
    const bool upper = ((t & 63) & sft) != 0;
#pragma unroll
    for (int i = 0; i < nv; ++i) {
      float keep = upper ? vals[i + nv] : vals[i];
      float send = upper ? vals[i] : vals[i + nv];
      vals[i] = keep + __shfl_xor(send, sft, 64);
    }
  }
  vals[0] += __shfl_xor(vals[0], 16, 64);
  vals[0] += __shfl_xor(vals[0], 32, 64);

  __shared__ float red[4][16];
  const int w = t >> 6, lane = t & 63;
  if (lane < 16) red[w][lane] = vals[0];
  __syncthreads();
  if (t < 16) {
    const float s = red[0][t] + red[1][t] + red[2][t] + red[3][t];
    const size_t base = ((size_t)nr * B_ + b) * F_ + f0;
    if (t < 8) p0[base + t] = s;
    else       p1[base + t - 8] = s;
  }
}

// ---------------------------------------------------------------------------
// K3 reduce: 8 blocks x 256 threads; thread = f. Sum NR partials in double,
// analytic epilogue (validated R3-R5):
//   A = (V0 + V1/Z1)/Z2, B = (V0 + 2 V1/Z1)/Z2^2,
//   Z2 = N+1+M2/2+M3/6, q = (N+2+2M2+(4/3)M3)/Z2^2, out = A + k(qA - B).
// ---------------------------------------------------------------------------
__global__ __launch_bounds__(256) void reduce_kernel(
    const float* __restrict__ p0, const float* __restrict__ p1,
    const float* __restrict__ pp, float* __restrict__ out) {
  const int b = blockIdx.x;
  const int t = threadIdx.x;  // = f

  double V0 = 0.0, V1 = 0.0;
#pragma unroll
  for (int nr = 0; nr < NR; ++nr) {
    const size_t base = ((size_t)nr * B_ + b) * F_ + t;
    V0 += (double)p0[base];
    V1 += (double)p1[base];
  }

  __shared__ double sc[3];
  if (t < 64) {
    double z1 = (double)pp[b * NCH + t];
    double w2 = (double)pp[B_ * NCH + b * NCH + t];
    double w3 = (double)pp[2 * B_ * NCH + b * NCH + t];
#pragma unroll
    for (int off = 32; off > 0; off >>= 1) {
      z1 += __shfl_xor(z1, off, 64);
      w2 += __shfl_xor(w2, off, 64);
      w3 += __shfl_xor(w3, off, 64);
    }
    if (t == 0) { sc[0] = z1; sc[1] = w2; sc[2] = w3; }
  }
  __syncthreads();

  const double z1 = sc[0], w2 = sc[1], w3 = sc[2];
  const double iZ1 = 1.0 / z1;
  const double M2 = w2 * iZ1 * iZ1;
  const double M3 = w3 * iZ1 * iZ1 * iZ1;
  const double Z2 = (double)N_ + 1.0 + 0.5 * M2 + M3 / 6.0;
  const double T2 = (double)N_ + 2.0 + 2.0 * M2 + (4.0 / 3.0) * M3;
  const double iZ2 = 1.0 / Z2;
  const double qd = T2 * iZ2 * iZ2;

  const double W1 = V1 * iZ1;
  const double A  = (V0 + W1) * iZ2;
  const double Bd = (V0 + 2.0 * W1) * iZ2 * iZ2;
  const double C  = qd * A - Bd;

  float* ob = out + (size_t)b * K_ * F_ + t;
#pragma unroll
  for (int k = 0; k < K_; ++k) ob[(size_t)k * F_] = (float)(A + (double)k * C);
}

extern "C" void kernel_launch(void* const* d_in, const int* in_sizes, int n_in,
                              void* d_out, int out_size, void* d_ws, size_t ws_size,
                              hipStream_t stream) {
  const float* q = (const float*)d_in[0];
  const float* keys = (const float*)d_in[1];
  const float* values = (const float*)d_in[2];
  float* out = (float*)d_out;
  float* e  = (float*)d_ws;                          // B*N floats = 1 MB
  float* p0 = e + (size_t)B_ * N_;                   // NR*B*F floats = 32 KB
  float* p1 = p0 + (size_t)NR * B_ * F_;             // 32 KB
  float* pp = p1 + (size_t)NR * B_ * F_;             // 3*B*64 floats

  expsim_kernel<<<dim3(B_ * NCH), dim3(512), 0, stream>>>(q, keys, e, pp);
  agg_kernel<<<dim3(B_ * 32 * NR), dim3(256), 0, stream>>>(e, values, p0, p1);
  reduce_kernel<<<dim3(B_), dim3(256), 0, stream>>>(p0, p1, pp, out);
}

// Round 8
// 114.908 us; speedup vs baseline: 1.2349x; 1.2349x over previous
//
#include <hip/hip_runtime.h>

#define B_ 8
#define D_ 256
#define N_ 32768
#define F_ 256
#define K_ 16
#define NCH 128       // K1 chunks per batch
#define CHN 256       // K1 n per chunk

__device__ __forceinline__ float sum4(float4 v) { return v.x + v.y + v.z + v.w; }
__device__ __forceinline__ float dot4(float4 a, float4 b) {
  return a.x * b.x + a.y * b.y + a.z * b.z + a.w * b.w;
}

// ---------------------------------------------------------------------------
// K1: e[b][n] = exp(-(q . k_n)/16) + per-chunk scalars (Se, Se2, Se3).
// 1024 blocks (8 b x 128 chunks of 256 n) x 256 threads = 4 blocks/CU,
// 16 waves/CU. Wave g owns d-quarter [g*64, g*64+64); lane c owns float4
// column c. 1 KB contiguous per load instruction.
// ---------------------------------------------------------------------------
__global__ __launch_bounds__(256) void expsim_kernel(
    const float* __restrict__ q, const float* __restrict__ keys,
    float* __restrict__ e, float4* __restrict__ scal) {
  const int b = blockIdx.x >> 7;
  const int ch = blockIdx.x & 127;
  const int t = threadIdx.x;
  const int c = t & 63;    // float4 column within chunk
  const int g = t >> 6;    // d-quarter == wave id

  __shared__ float qs[D_];
  __shared__ float4 part[3][64];

  qs[t] = q[b * D_ + t];
  __syncthreads();

  const int n0 = ch * CHN + c * 4;
  const float* kp = keys + (size_t)b * D_ * N_ + (size_t)(g * 64) * N_ + n0;
  const float* qg = qs + g * 64;
  float ax = 0.f, ay = 0.f, az = 0.f, aw = 0.f;
#pragma unroll 8
  for (int d = 0; d < 64; ++d) {
    float4 kv = *reinterpret_cast<const float4*>(kp + (size_t)d * N_);
    float qd = qg[d];
    ax += qd * kv.x; ay += qd * kv.y; az += qd * kv.z; aw += qd * kv.w;
  }
  if (g > 0) part[g - 1][c] = make_float4(ax, ay, az, aw);
  __syncthreads();

  if (g == 0) {
    float4 p1 = part[0][c], p2 = part[1][c], p3 = part[2][c];
    float4 ev;
    ev.x = __expf(-0.0625f * (ax + p1.x + p2.x + p3.x));
    ev.y = __expf(-0.0625f * (ay + p1.y + p2.y + p3.y));
    ev.z = __expf(-0.0625f * (az + p1.z + p2.z + p3.z));
    ev.w = __expf(-0.0625f * (aw + p1.w + p2.w + p3.w));
    *reinterpret_cast<float4*>(e + (size_t)b * N_ + n0) = ev;
    float4 e2 = make_float4(ev.x * ev.x, ev.y * ev.y, ev.z * ev.z, ev.w * ev.w);
    float s1 = sum4(ev);
    float s2 = sum4(e2);
    float s3 = e2.x * ev.x + e2.y * ev.y + e2.z * ev.z + e2.w * ev.w;
    // wave 0 covers all 256 n of the chunk; reduce within the wave
#pragma unroll
    for (int off = 32; off > 0; off >>= 1) {
      s1 += __shfl_xor(s1, off, 64);
      s2 += __shfl_xor(s2, off, 64);
      s3 += __shfl_xor(s3, off, 64);
    }
    if (t == 0) scal[b * NCH + ch] = make_float4(s1, s2, s3, 0.f);
  }
}

// ---------------------------------------------------------------------------
// K2: moment aggregation, ONE f-row per block.
// 2048 blocks (b = bid&7 -> XCD/L2 affinity for e[b]; f = bid>>3) x 256 thr
// = 8 blocks/CU = 32 waves/CU. Loop body: 2 float4 loads + 2 FMAs. Maximum
// outstanding-load capacity; zero cross-lane ops until the tail.
// ---------------------------------------------------------------------------
__global__ __launch_bounds__(256, 8) void agg_kernel(
    const float* __restrict__ e, const float* __restrict__ values,
    float* __restrict__ p0, float* __restrict__ p1) {
  const int b = blockIdx.x & 7;
  const int f = blockIdx.x >> 3;
  const int t = threadIdx.x;
  const float* eb = e + (size_t)b * N_ + t * 4;
  const float* vb = values + ((size_t)b * F_ + f) * N_ + t * 4;

  float m0 = 0.f, m1 = 0.f;
#pragma unroll 4
  for (int it = 0; it < 32; ++it) {
    const int off = it * 1024;
    float4 v4 = *reinterpret_cast<const float4*>(vb + off);
    float4 e4 = *reinterpret_cast<const float4*>(eb + off);
    m0 += sum4(v4);
    m1 += dot4(v4, e4);
  }

#pragma unroll
  for (int off = 32; off > 0; off >>= 1) {
    m0 += __shfl_xor(m0, off, 64);
    m1 += __shfl_xor(m1, off, 64);
  }

  __shared__ float red[4][2];
  const int w = t >> 6, lane = t & 63;
  if (lane == 0) { red[w][0] = m0; red[w][1] = m1; }
  __syncthreads();
  if (t == 0) {
    p0[(size_t)b * F_ + f] = red[0][0] + red[1][0] + red[2][0] + red[3][0];
    p1[(size_t)b * F_ + f] = red[0][1] + red[1][1] + red[2][1] + red[3][1];
  }
}

// ---------------------------------------------------------------------------
// K3 reduce: 8 blocks x 256 threads; thread = f. Analytic epilogue
// (validated R3-R6):
//   A = (V0 + V1/Z1)/Z2, B = (V0 + 2 V1/Z1)/Z2^2,
//   Z2 = N+1+M2/2+M3/6, q = (N+2+2M2+(4/3)M3)/Z2^2, out = A + k(qA - B).
// ---------------------------------------------------------------------------
__global__ __launch_bounds__(256) void reduce_kernel(
    const float* __restrict__ p0, const float* __restrict__ p1,
    const float4* __restrict__ scal, float* __restrict__ out) {
  const int b = blockIdx.x;
  const int t = threadIdx.x;  // = f

  const double V0 = (double)p0[(size_t)b * F_ + t];
  const double V1 = (double)p1[(size_t)b * F_ + t];

  __shared__ double wred[2][3];
  __shared__ double sc[3];
  if (t < 128) {
    float4 s = scal[b * NCH + t];
    double z1 = (double)s.x, w2 = (double)s.y, w3 = (double)s.z;
#pragma unroll
    for (int off = 32; off > 0; off >>= 1) {
      z1 += __shfl_xor(z1, off, 64);
      w2 += __shfl_xor(w2, off, 64);
      w3 += __shfl_xor(w3, off, 64);
    }
    if ((t & 63) == 0) {
      wred[t >> 6][0] = z1; wred[t >> 6][1] = w2; wred[t >> 6][2] = w3;
    }
  }
  __syncthreads();
  if (t == 0) {
    sc[0] = wred[0][0] + wred[1][0];
    sc[1] = wred[0][1] + wred[1][1];
    sc[2] = wred[0][2] + wred[1][2];
  }
  __syncthreads();

  const double z1 = sc[0], w2 = sc[1], w3 = sc[2];
  const double iZ1 = 1.0 / z1;
  const double M2 = w2 * iZ1 * iZ1;
  const double M3 = w3 * iZ1 * iZ1 * iZ1;
  const double Z2 = (double)N_ + 1.0 + 0.5 * M2 + M3 / 6.0;
  const double T2 = (double)N_ + 2.0 + 2.0 * M2 + (4.0 / 3.0) * M3;
  const double iZ2 = 1.0 / Z2;
  const double qd = T2 * iZ2 * iZ2;

  const double W1 = V1 * iZ1;
  const double A  = (V0 + W1) * iZ2;
  const double Bd = (V0 + 2.0 * W1) * iZ2 * iZ2;
  const double C  = qd * A - Bd;

  float* ob = out + (size_t)b * K_ * F_ + t;
#pragma unroll
  for (int k = 0; k < K_; ++k) ob[(size_t)k * F_] = (float)(A + (double)k * C);
}

extern "C" void kernel_launch(void* const* d_in, const int* in_sizes, int n_in,
                              void* d_out, int out_size, void* d_ws, size_t ws_size,
                              hipStream_t stream) {
  const float* q = (const float*)d_in[0];
  const float* keys = (const float*)d_in[1];
  const float* values = (const float*)d_in[2];
  float* out = (float*)d_out;
  float* e  = (float*)d_ws;                          // B*N floats = 1 MB
  float* p0 = e + (size_t)B_ * N_;                   // B*F floats = 8 KB
  float* p1 = p0 + (size_t)B_ * F_;                  // 8 KB
  float4* scal = (float4*)(p1 + (size_t)B_ * F_);    // B*NCH float4 = 16 KB

  expsim_kernel<<<dim3(B_ * NCH), dim3(256), 0, stream>>>(q, keys, e, scal);
  agg_kernel<<<dim3(B_ * F_), dim3(256), 0, stream>>>(e, values, p0, p1);
  reduce_kernel<<<dim3(B_), dim3(256), 0, stream>>>(p0, p1, scal, out);
}

// Round 9
// 108.342 us; speedup vs baseline: 1.3097x; 1.0606x over previous
//
#include <hip/hip_runtime.h>

#define B_ 8
#define D_ 256
#define N_ 32768
#define F_ 256
#define K_ 16
#define NCH 64        // K1 chunks per batch
#define CHN 512       // K1 n per chunk

__device__ __forceinline__ float sum4(float4 v) { return v.x + v.y + v.z + v.w; }
__device__ __forceinline__ float dot4(float4 a, float4 b) {
  return a.x * b.x + a.y * b.y + a.z * b.z + a.w * b.w;
}

// ---------------------------------------------------------------------------
// K1 (R2-verbatim, part of the 108.7/109.7 best runs):
// e[b][n] = exp(-(q . k_n)/16) + per-chunk scalars (Se, Se2, Se3).
// 512 blocks (8 b x 64 chunks of 512 n) x 512 threads.
// ---------------------------------------------------------------------------
__global__ __launch_bounds__(512) void expsim_kernel(
    const float* __restrict__ q, const float* __restrict__ keys,
    float* __restrict__ e, float4* __restrict__ scal) {
  const int b = blockIdx.x >> 6;
  const int chunk = blockIdx.x & 63;
  const int t = threadIdx.x;
  const int c = t & 127;
  const int g = t >> 7;
  __shared__ float qs[D_];
  __shared__ float4 part[3][128];
  __shared__ float pr[8][3];
  if (t < D_) qs[t] = q[b * D_ + t];
  __syncthreads();
  const int n0 = chunk * CHN + c * 4;
  const float* kp = keys + (size_t)b * D_ * N_ + (size_t)(g * 64) * N_ + n0;
  const float* qg = qs + g * 64;
  float ax = 0.f, ay = 0.f, az = 0.f, aw = 0.f;
#pragma unroll 8
  for (int d = 0; d < 64; ++d) {
    float4 kv = *reinterpret_cast<const float4*>(kp + (size_t)d * N_);
    float qd = qg[d];
    ax += qd * kv.x; ay += qd * kv.y; az += qd * kv.z; aw += qd * kv.w;
  }
  if (g > 0) part[g - 1][c] = make_float4(ax, ay, az, aw);
  __syncthreads();
  float s1 = 0.f, s2 = 0.f, s3 = 0.f;
  if (g == 0) {
    float4 p1 = part[0][c], p2 = part[1][c], p3 = part[2][c];
    float4 ev;
    ev.x = __expf(-0.0625f * (ax + p1.x + p2.x + p3.x));
    ev.y = __expf(-0.0625f * (ay + p1.y + p2.y + p3.y));
    ev.z = __expf(-0.0625f * (az + p1.z + p2.z + p3.z));
    ev.w = __expf(-0.0625f * (aw + p1.w + p2.w + p3.w));
    *reinterpret_cast<float4*>(e + (size_t)b * N_ + n0) = ev;
    float4 e2 = make_float4(ev.x * ev.x, ev.y * ev.y, ev.z * ev.z, ev.w * ev.w);
    s1 = sum4(ev);
    s2 = sum4(e2);
    s3 = e2.x * ev.x + e2.y * ev.y + e2.z * ev.z + e2.w * ev.w;
  }
#pragma unroll
  for (int off = 32; off > 0; off >>= 1) {
    s1 += __shfl_xor(s1, off, 64);
    s2 += __shfl_xor(s2, off, 64);
    s3 += __shfl_xor(s3, off, 64);
  }
  if ((t & 63) == 0) { pr[t >> 6][0] = s1; pr[t >> 6][1] = s2; pr[t >> 6][2] = s3; }
  __syncthreads();
  if (t == 0) {
    float r1 = 0.f, r2 = 0.f, r3 = 0.f;
#pragma unroll
    for (int w = 0; w < 8; ++w) { r1 += pr[w][0]; r2 += pr[w][1]; r3 += pr[w][2]; }
    scal[b * NCH + chunk] = make_float4(r1, r2, r3, 0.f);
  }
}

// ---------------------------------------------------------------------------
// K2: moment aggregation (R2's proven 2f shape) + FUSED analytic epilogue.
// 1024 blocks (b = bid&7 -> XCD/L2 affinity for e[b]; 128 f-pairs) x 256 thr,
// 4 blocks/CU. Streaming loop: e4 loaded once, used for 2 value rows.
// Tail: block-reduce V0/V1 per f; wave 0 reduces the 64 chunk-scalars in
// double; epilogue out[b][k][f] = A + k(qA - B)  (validated R3-R7 math):
//   A = (V0 + V1/Z1)/Z2, B = (V0 + 2 V1/Z1)/Z2^2,
//   Z2 = N+1+M2/2+M3/6,  q = (N+2+2M2+(4/3)M3)/Z2^2.
// ---------------------------------------------------------------------------
__global__ __launch_bounds__(256) void agg_kernel(
    const float* __restrict__ e, const float* __restrict__ values,
    const float4* __restrict__ scal, float* __restrict__ out) {
  const int b = blockIdx.x & 7;
  const int f0 = (blockIdx.x >> 3) * 2;
  const int t = threadIdx.x;
  const float* eb = e + (size_t)b * N_ + t * 4;
  const float* vp0 = values + ((size_t)b * F_ + f0) * N_ + t * 4;
  const float* vp1 = vp0 + N_;

  float m0a = 0.f, m1a = 0.f, m0b = 0.f, m1b = 0.f;
#pragma unroll 4
  for (int it = 0; it < 32; ++it) {
    const int off = it * 1024;
    float4 e4 = *reinterpret_cast<const float4*>(eb + off);
    float4 va = *reinterpret_cast<const float4*>(vp0 + off);
    float4 vb = *reinterpret_cast<const float4*>(vp1 + off);
    m0a += sum4(va);
    m1a += dot4(va, e4);
    m0b += sum4(vb);
    m1b += dot4(vb, e4);
  }

#pragma unroll
  for (int off = 32; off > 0; off >>= 1) {
    m0a += __shfl_xor(m0a, off, 64);
    m1a += __shfl_xor(m1a, off, 64);
    m0b += __shfl_xor(m0b, off, 64);
    m1b += __shfl_xor(m1b, off, 64);
  }

  __shared__ float red[4][4];
  __shared__ double dsc[4];   // A0, C0, A1, C1
  const int w = t >> 6, lane = t & 63;
  if (lane == 0) {
    red[w][0] = m0a; red[w][1] = m1a; red[w][2] = m0b; red[w][3] = m1b;
  }
  __syncthreads();

  if (t < 64) {
    // wave 0: scalar chunk-sum reduce (64 entries, 1 per lane) in double
    float4 s = scal[b * NCH + t];
    double z1 = (double)s.x, w2 = (double)s.y, w3 = (double)s.z;
#pragma unroll
    for (int off = 32; off > 0; off >>= 1) {
      z1 += __shfl_xor(z1, off, 64);
      w2 += __shfl_xor(w2, off, 64);
      w3 += __shfl_xor(w3, off, 64);
    }
    if (t == 0) {
      const double iZ1 = 1.0 / z1;
      const double M2 = w2 * iZ1 * iZ1;
      const double M3 = w3 * iZ1 * iZ1 * iZ1;
      const double Z2 = (double)N_ + 1.0 + 0.5 * M2 + M3 / 6.0;
      const double T2 = (double)N_ + 2.0 + 2.0 * M2 + (4.0 / 3.0) * M3;
      const double iZ2 = 1.0 / Z2;
      const double qd = T2 * iZ2 * iZ2;
#pragma unroll
      for (int f = 0; f < 2; ++f) {
        const double V0 = (double)red[0][f * 2] + (double)red[1][f * 2] +
                          (double)red[2][f * 2] + (double)red[3][f * 2];
        const double V1 = (double)red[0][f * 2 + 1] + (double)red[1][f * 2 + 1] +
                          (double)red[2][f * 2 + 1] + (double)red[3][f * 2 + 1];
        const double W1 = V1 * iZ1;
        const double A  = (V0 + W1) * iZ2;
        const double Bd = (V0 + 2.0 * W1) * iZ2 * iZ2;
        dsc[f * 2]     = A;
        dsc[f * 2 + 1] = qd * A - Bd;
      }
    }
  }
  __syncthreads();
  if (t < 32) {
    const int k = t & 15, f = t >> 4;
    const double A = dsc[f * 2], C = dsc[f * 2 + 1];
    out[((size_t)b * K_ + k) * F_ + f0 + f] = (float)(A + (double)k * C);
  }
}

extern "C" void kernel_launch(void* const* d_in, const int* in_sizes, int n_in,
                              void* d_out, int out_size, void* d_ws, size_t ws_size,
                              hipStream_t stream) {
  const float* q = (const float*)d_in[0];
  const float* keys = (const float*)d_in[1];
  const float* values = (const float*)d_in[2];
  float* out = (float*)d_out;
  float* e = (float*)d_ws;                           // B*N floats = 1 MB
  float4* scal = (float4*)(e + (size_t)B_ * N_);     // B*NCH float4 = 8 KB

  expsim_kernel<<<dim3(B_ * NCH), dim3(512), 0, stream>>>(q, keys, e, scal);
  agg_kernel<<<dim3(B_ * (F_ / 2)), dim3(256), 0, stream>>>(e, values, scal, out);
}

// Round 11
// 99.487 us; speedup vs baseline: 1.4263x; 1.0890x over previous
//
#include <hip/hip_runtime.h>

#define B_ 8
#define D_ 256
#define N_ 32768
#define F_ 256
#define K_ 16
#define NCH 64        // K1 chunks per batch
#define CHN 512       // K1 n per chunk

__device__ __forceinline__ float sum4(float4 v) { return v.x + v.y + v.z + v.w; }
__device__ __forceinline__ float dot4(float4 a, float4 b) {
  return a.x * b.x + a.y * b.y + a.z * b.z + a.w * b.w;
}

// ---------------------------------------------------------------------------
// K1 (R2-structure; block index remapped so b = bid&7 matches agg's XCD
// affinity -> e[b] written and re-read on the same XCD's L2):
// e[b][n] = exp(-(q . k_n)/16) + per-chunk scalars (Se, Se2, Se3).
// 512 blocks x 512 threads.
// ---------------------------------------------------------------------------
__global__ __launch_bounds__(512) void expsim_kernel(
    const float* __restrict__ q, const float* __restrict__ keys,
    float* __restrict__ e, float4* __restrict__ scal) {
  const int b = blockIdx.x & 7;
  const int chunk = blockIdx.x >> 3;
  const int t = threadIdx.x;
  const int c = t & 127;
  const int g = t >> 7;
  __shared__ float qs[D_];
  __shared__ float4 part[3][128];
  __shared__ float pr[8][3];
  if (t < D_) qs[t] = q[b * D_ + t];
  __syncthreads();
  const int n0 = chunk * CHN + c * 4;
  const float* kp = keys + (size_t)b * D_ * N_ + (size_t)(g * 64) * N_ + n0;
  const float* qg = qs + g * 64;
  float ax = 0.f, ay = 0.f, az = 0.f, aw = 0.f;
#pragma unroll 8
  for (int d = 0; d < 64; ++d) {
    float4 kv = *reinterpret_cast<const float4*>(kp + (size_t)d * N_);
    float qd = qg[d];
    ax += qd * kv.x; ay += qd * kv.y; az += qd * kv.z; aw += qd * kv.w;
  }
  if (g > 0) part[g - 1][c] = make_float4(ax, ay, az, aw);
  __syncthreads();
  float s1 = 0.f, s2 = 0.f, s3 = 0.f;
  if (g == 0) {
    float4 p1 = part[0][c], p2 = part[1][c], p3 = part[2][c];
    float4 ev;
    ev.x = __expf(-0.0625f * (ax + p1.x + p2.x + p3.x));
    ev.y = __expf(-0.0625f * (ay + p1.y + p2.y + p3.y));
    ev.z = __expf(-0.0625f * (az + p1.z + p2.z + p3.z));
    ev.w = __expf(-0.0625f * (aw + p1.w + p2.w + p3.w));
    *reinterpret_cast<float4*>(e + (size_t)b * N_ + n0) = ev;
    float4 e2 = make_float4(ev.x * ev.x, ev.y * ev.y, ev.z * ev.z, ev.w * ev.w);
    s1 = sum4(ev);
    s2 = sum4(e2);
    s3 = e2.x * ev.x + e2.y * ev.y + e2.z * ev.z + e2.w * ev.w;
  }
#pragma unroll
  for (int off = 32; off > 0; off >>= 1) {
    s1 += __shfl_xor(s1, off, 64);
    s2 += __shfl_xor(s2, off, 64);
    s3 += __shfl_xor(s3, off, 64);
  }
  if ((t & 63) == 0) { pr[t >> 6][0] = s1; pr[t >> 6][1] = s2; pr[t >> 6][2] = s3; }
  __syncthreads();
  if (t == 0) {
    float r1 = 0.f, r2 = 0.f, r3 = 0.f;
#pragma unroll
    for (int w = 0; w < 8; ++w) { r1 += pr[w][0]; r2 += pr[w][1]; r3 += pr[w][2]; }
    scal[b * NCH + chunk] = make_float4(r1, r2, r3, 0.f);
  }
}

// ---------------------------------------------------------------------------
// K2 (R8-verbatim): moment aggregation + FUSED analytic epilogue.
// 1024 blocks (b = bid&7 -> XCD/L2 affinity for e[b]; 128 f-pairs) x 256 thr,
// 4 blocks/CU. Streaming loop: e4 loaded once, used for 2 value rows.
// Tail: block-reduce V0/V1 per f; wave 0 reduces the 64 chunk-scalars in
// double; epilogue out[b][k][f] = A + k(qA - B)  (validated R3-R8 math):
//   A = (V0 + V1/Z1)/Z2, B = (V0 + 2 V1/Z1)/Z2^2,
//   Z2 = N+1+M2/2+M3/6,  q = (N+2+2M2+(4/3)M3)/Z2^2.
// ---------------------------------------------------------------------------
__global__ __launch_bounds__(256) void agg_kernel(
    const float* __restrict__ e, const float* __restrict__ values,
    const float4* __restrict__ scal, float* __restrict__ out) {
  const int b = blockIdx.x & 7;
  const int f0 = (blockIdx.x >> 3) * 2;
  const int t = threadIdx.x;
  const float* eb = e + (size_t)b * N_ + t * 4;
  const float* vp0 = values + ((size_t)b * F_ + f0) * N_ + t * 4;
  const float* vp1 = vp0 + N_;

  float m0a = 0.f, m1a = 0.f, m0b = 0.f, m1b = 0.f;
#pragma unroll 4
  for (int it = 0; it < 32; ++it) {
    const int off = it * 1024;
    float4 e4 = *reinterpret_cast<const float4*>(eb + off);
    float4 va = *reinterpret_cast<const float4*>(vp0 + off);
    float4 vb = *reinterpret_cast<const float4*>(vp1 + off);
    m0a += sum4(va);
    m1a += dot4(va, e4);
    m0b += sum4(vb);
    m1b += dot4(vb, e4);
  }

#pragma unroll
  for (int off = 32; off > 0; off >>= 1) {
    m0a += __shfl_xor(m0a, off, 64);
    m1a += __shfl_xor(m1a, off, 64);
    m0b += __shfl_xor(m0b, off, 64);
    m1b += __shfl_xor(m1b, off, 64);
  }

  __shared__ float red[4][4];
  __shared__ double dsc[4];   // A0, C0, A1, C1
  const int w = t >> 6, lane = t & 63;
  if (lane == 0) {
    red[w][0] = m0a; red[w][1] = m1a; red[w][2] = m0b; red[w][3] = m1b;
  }
  __syncthreads();

  if (t < 64) {
    // wave 0: scalar chunk-sum reduce (64 entries, 1 per lane) in double
    float4 s = scal[b * NCH + t];
    double z1 = (double)s.x, w2 = (double)s.y, w3 = (double)s.z;
#pragma unroll
    for (int off = 32; off > 0; off >>= 1) {
      z1 += __shfl_xor(z1, off, 64);
      w2 += __shfl_xor(w2, off, 64);
      w3 += __shfl_xor(w3, off, 64);
    }
    if (t == 0) {
      const double iZ1 = 1.0 / z1;
      const double M2 = w2 * iZ1 * iZ1;
      const double M3 = w3 * iZ1 * iZ1 * iZ1;
      const double Z2 = (double)N_ + 1.0 + 0.5 * M2 + M3 / 6.0;
      const double T2 = (double)N_ + 2.0 + 2.0 * M2 + (4.0 / 3.0) * M3;
      const double iZ2 = 1.0 / Z2;
      const double qd = T2 * iZ2 * iZ2;
#pragma unroll
      for (int f = 0; f < 2; ++f) {
        const double V0 = (double)red[0][f * 2] + (double)red[1][f * 2] +
                          (double)red[2][f * 2] + (double)red[3][f * 2];
        const double V1 = (double)red[0][f * 2 + 1] + (double)red[1][f * 2 + 1] +
                          (double)red[2][f * 2 + 1] + (double)red[3][f * 2 + 1];
        const double W1 = V1 * iZ1;
        const double A  = (V0 + W1) * iZ2;
        const double Bd = (V0 + 2.0 * W1) * iZ2 * iZ2;
        dsc[f * 2]     = A;
        dsc[f * 2 + 1] = qd * A - Bd;
      }
    }
  }
  __syncthreads();
  if (t < 32) {
    const int k = t & 15, f = t >> 4;
    const double A = dsc[f * 2], C = dsc[f * 2 + 1];
    out[((size_t)b * K_ + k) * F_ + f0 + f] = (float)(A + (double)k * C);
  }
}

extern "C" void kernel_launch(void* const* d_in, const int* in_sizes, int n_in,
                              void* d_out, int out_size, void* d_ws, size_t ws_size,
                              hipStream_t stream) {
  const float* q = (const float*)d_in[0];
  const float* keys = (const float*)d_in[1];
  const float* values = (const float*)d_in[2];
  float* out = (float*)d_out;
  float* e = (float*)d_ws;                           // B*N floats = 1 MB
  float4* scal = (float4*)(e + (size_t)B_ * N_);     // B*NCH float4 = 8 KB

  expsim_kernel<<<dim3(B_ * NCH), dim3(512), 0, stream>>>(q, keys, e, scal);
  agg_kernel<<<dim3(B_ * (F_ / 2)), dim3(256), 0, stream>>>(e, values, scal, out);
}

// Round 12
// 98.702 us; speedup vs baseline: 1.4376x; 1.0080x over previous
//
#include <hip/hip_runtime.h>

#define B_ 8
#define D_ 256
#define N_ 32768
#define F_ 256
#define K_ 16
#define NCH 64        // K1 chunks per batch
#define CHN 512       // K1 n per chunk

__device__ __forceinline__ float sum4(float4 v) { return v.x + v.y + v.z + v.w; }
__device__ __forceinline__ float dot4(float4 a, float4 b) {
  return a.x * b.x + a.y * b.y + a.z * b.z + a.w * b.w;
}

// ---------------------------------------------------------------------------
// K1 (R10-verbatim, 99.5µs run): b = bid&7 XCD affinity so e[b] is written
// and re-read on the same XCD's L2.
// e[b][n] = exp(-(q . k_n)/16) + per-chunk scalars (Se, Se2, Se3).
// 512 blocks x 512 threads.
// ---------------------------------------------------------------------------
__global__ __launch_bounds__(512) void expsim_kernel(
    const float* __restrict__ q, const float* __restrict__ keys,
    float* __restrict__ e, float4* __restrict__ scal) {
  const int b = blockIdx.x & 7;
  const int chunk = blockIdx.x >> 3;
  const int t = threadIdx.x;
  const int c = t & 127;
  const int g = t >> 7;
  __shared__ float qs[D_];
  __shared__ float4 part[3][128];
  __shared__ float pr[8][3];
  if (t < D_) qs[t] = q[b * D_ + t];
  __syncthreads();
  const int n0 = chunk * CHN + c * 4;
  const float* kp = keys + (size_t)b * D_ * N_ + (size_t)(g * 64) * N_ + n0;
  const float* qg = qs + g * 64;
  float ax = 0.f, ay = 0.f, az = 0.f, aw = 0.f;
#pragma unroll 8
  for (int d = 0; d < 64; ++d) {
    float4 kv = *reinterpret_cast<const float4*>(kp + (size_t)d * N_);
    float qd = qg[d];
    ax += qd * kv.x; ay += qd * kv.y; az += qd * kv.z; aw += qd * kv.w;
  }
  if (g > 0) part[g - 1][c] = make_float4(ax, ay, az, aw);
  __syncthreads();
  float s1 = 0.f, s2 = 0.f, s3 = 0.f;
  if (g == 0) {
    float4 p1 = part[0][c], p2 = part[1][c], p3 = part[2][c];
    float4 ev;
    ev.x = __expf(-0.0625f * (ax + p1.x + p2.x + p3.x));
    ev.y = __expf(-0.0625f * (ay + p1.y + p2.y + p3.y));
    ev.z = __expf(-0.0625f * (az + p1.z + p2.z + p3.z));
    ev.w = __expf(-0.0625f * (aw + p1.w + p2.w + p3.w));
    *reinterpret_cast<float4*>(e + (size_t)b * N_ + n0) = ev;
    float4 e2 = make_float4(ev.x * ev.x, ev.y * ev.y, ev.z * ev.z, ev.w * ev.w);
    s1 = sum4(ev);
    s2 = sum4(e2);
    s3 = e2.x * ev.x + e2.y * ev.y + e2.z * ev.z + e2.w * ev.w;
  }
#pragma unroll
  for (int off = 32; off > 0; off >>= 1) {
    s1 += __shfl_xor(s1, off, 64);
    s2 += __shfl_xor(s2, off, 64);
    s3 += __shfl_xor(s3, off, 64);
  }
  if ((t & 63) == 0) { pr[t >> 6][0] = s1; pr[t >> 6][1] = s2; pr[t >> 6][2] = s3; }
  __syncthreads();
  if (t == 0) {
    float r1 = 0.f, r2 = 0.f, r3 = 0.f;
#pragma unroll
    for (int w = 0; w < 8; ++w) { r1 += pr[w][0]; r2 += pr[w][1]; r3 += pr[w][2]; }
    scal[b * NCH + chunk] = make_float4(r1, r2, r3, 0.f);
  }
}

// ---------------------------------------------------------------------------
// K2: moment aggregation, 4 f-rows per block (halves L2 e-traffic vs R8's 2f:
// 64 MB/XCD instead of 128, and 17% fewer load instructions per value-byte).
// 512 blocks (b = bid&7 XCD affinity; 64 f-quads) x 512 threads = 2/CU,
// 16 waves/CU (same wave count as R8's 1024x256). Fused analytic epilogue
// (validated R3-R10):
//   A = (V0 + V1/Z1)/Z2, B = (V0 + 2 V1/Z1)/Z2^2,
//   Z2 = N+1+M2/2+M3/6,  q = (N+2+2M2+(4/3)M3)/Z2^2,
//   out[b][k][f] = A + k (q A - B).
// ---------------------------------------------------------------------------
__global__ __launch_bounds__(512) void agg_kernel(
    const float* __restrict__ e, const float* __restrict__ values,
    const float4* __restrict__ scal, float* __restrict__ out) {
  const int b = blockIdx.x & 7;
  const int f0 = (blockIdx.x >> 3) * 4;
  const int t = threadIdx.x;
  const float* eb = e + (size_t)b * N_ + t * 4;
  const float* vb = values + ((size_t)b * F_ + f0) * N_ + t * 4;

  float m0[4] = {0.f, 0.f, 0.f, 0.f};
  float m1[4] = {0.f, 0.f, 0.f, 0.f};
#pragma unroll 2
  for (int it = 0; it < 16; ++it) {
    const int off = it * 2048;
    float4 e4 = *reinterpret_cast<const float4*>(eb + off);
#pragma unroll
    for (int j = 0; j < 4; ++j) {
      float4 v4 = *reinterpret_cast<const float4*>(vb + (size_t)j * N_ + off);
      m0[j] += sum4(v4);
      m1[j] += dot4(v4, e4);
    }
  }

#pragma unroll
  for (int j = 0; j < 4; ++j) {
#pragma unroll
    for (int off = 32; off > 0; off >>= 1) {
      m0[j] += __shfl_xor(m0[j], off, 64);
      m1[j] += __shfl_xor(m1[j], off, 64);
    }
  }

  __shared__ float red[8][8];
  __shared__ double dsc[8];   // (A, C) per f
  const int w = t >> 6, lane = t & 63;
  if (lane == 0) {
#pragma unroll
    for (int j = 0; j < 4; ++j) { red[w][j * 2] = m0[j]; red[w][j * 2 + 1] = m1[j]; }
  }
  __syncthreads();

  if (t < 64) {
    // wave 0: scalar chunk-sum reduce (64 entries, 1 per lane) in double
    float4 s = scal[b * NCH + t];
    double z1 = (double)s.x, w2 = (double)s.y, w3 = (double)s.z;
#pragma unroll
    for (int off = 32; off > 0; off >>= 1) {
      z1 += __shfl_xor(z1, off, 64);
      w2 += __shfl_xor(w2, off, 64);
      w3 += __shfl_xor(w3, off, 64);
    }
    if (t == 0) {
      const double iZ1 = 1.0 / z1;
      const double M2 = w2 * iZ1 * iZ1;
      const double M3 = w3 * iZ1 * iZ1 * iZ1;
      const double Z2 = (double)N_ + 1.0 + 0.5 * M2 + M3 / 6.0;
      const double T2 = (double)N_ + 2.0 + 2.0 * M2 + (4.0 / 3.0) * M3;
      const double iZ2 = 1.0 / Z2;
      const double qd = T2 * iZ2 * iZ2;
#pragma unroll
      for (int f = 0; f < 4; ++f) {
        double V0 = 0.0, V1 = 0.0;
#pragma unroll
        for (int wv = 0; wv < 8; ++wv) {
          V0 += (double)red[wv][f * 2];
          V1 += (double)red[wv][f * 2 + 1];
        }
        const double W1 = V1 * iZ1;
        const double A  = (V0 + W1) * iZ2;
        const double Bd = (V0 + 2.0 * W1) * iZ2 * iZ2;
        dsc[f * 2]     = A;
        dsc[f * 2 + 1] = qd * A - Bd;
      }
    }
  }
  __syncthreads();
  if (t < 64) {
    const int k = t & 15, f = t >> 4;
    const double A = dsc[f * 2], C = dsc[f * 2 + 1];
    out[((size_t)b * K_ + k) * F_ + f0 + f] = (float)(A + (double)k * C);
  }
}

extern "C" void kernel_launch(void* const* d_in, const int* in_sizes, int n_in,
                              void* d_out, int out_size, void* d_ws, size_t ws_size,
                              hipStream_t stream) {
  const float* q = (const float*)d_in[0];
  const float* keys = (const float*)d_in[1];
  const float* values = (const float*)d_in[2];
  float* out = (float*)d_out;
  float* e = (float*)d_ws;                           // B*N floats = 1 MB
  float4* scal = (float4*)(e + (size_t)B_ * N_);     // B*NCH float4 = 8 KB

  expsim_kernel<<<dim3(B_ * NCH), dim3(512), 0, stream>>>(q, keys, e, scal);
  agg_kernel<<<dim3(B_ * (F_ / 4)), dim3(512), 0, stream>>>(e, values, scal, out);
}